// Round 3
// baseline (1201.553 us; speedup 1.0000x reference)
//
#include <hip/hip_runtime.h>
#include <stdint.h>

typedef __attribute__((ext_vector_type(8))) short bf16x8;
typedef __attribute__((ext_vector_type(4))) float f32x4;
typedef __attribute__((ext_vector_type(8))) unsigned short us8;

#define E_CNT 262144
#define T_CNT 1048576

static __device__ __forceinline__ unsigned short f2bf_u(float f) {
  __bf16 h = (__bf16)f;
  return __builtin_bit_cast(unsigned short, h);
}
static __device__ __forceinline__ uint32_t pack2bf(float a, float b) {
  return (uint32_t)f2bf_u(a) | ((uint32_t)f2bf_u(b) << 16);
}
static __device__ __forceinline__ float silu_f(float v) {
  float e = __builtin_amdgcn_exp2f(v * -1.44269504088896341f);
  return v * __builtin_amdgcn_rcpf(1.0f + e);
}
static __device__ __forceinline__ void gl_lds16(const void* g, void* l) {
  __builtin_amdgcn_global_load_lds(
      (const __attribute__((address_space(1))) void*)g,
      (__attribute__((address_space(3))) void*)l, 16, 0, 0);
}

// ---------------------------------------------------------------------------
// 4-layer MLP on one wave's 16 rows. x lives bf16-swizzled in the wave's
// 4KB xb slice; weights are LDS-resident fragment-linear (lane*16 reads).
// Layers 1-3: +bias, silu, write back to slice. Layer 4: f32 nt-store.
// ---------------------------------------------------------------------------
static __device__ __forceinline__ void mlp4_store(
    const char* __restrict__ Wb, char* __restrict__ slice,
    const float* __restrict__ b1, const float* __restrict__ b2,
    const float* __restrict__ b3, float* __restrict__ outPtr,
    int l15, int q, int lane, int swz)
{
  #pragma unroll
  for (int L = 0; L < 4; ++L) {
    f32x4 acc[8];
    #pragma unroll
    for (int ct = 0; ct < 8; ++ct) { f32x4 z = {0.f,0.f,0.f,0.f}; acc[ct] = z; }
    #pragma unroll
    for (int ks = 0; ks < 4; ++ks) {
      bf16x8 xf = *(const bf16x8*)(slice + ((l15 * 256 + ks * 64 + q * 16) ^ swz));
      #pragma unroll
      for (int ct = 0; ct < 8; ++ct) {
        bf16x8 wf = *(const bf16x8*)(Wb + (((L * 8 + ct) * 4 + ks) << 10) + lane * 16);
        acc[ct] = __builtin_amdgcn_mfma_f32_16x16x32_bf16(wf, xf, acc[ct], 0, 0, 0);
      }
    }
    if (L < 3) {
      const float* bp = (L == 0) ? b1 : (L == 1) ? b2 : b3;
      #pragma unroll
      for (int ct = 0; ct < 8; ++ct) {
        f32x4 bv = *(const f32x4*)(bp + ct * 16 + q * 4);
        float v0 = silu_f(acc[ct][0] + bv[0]);
        float v1 = silu_f(acc[ct][1] + bv[1]);
        float v2 = silu_f(acc[ct][2] + bv[2]);
        float v3 = silu_f(acc[ct][3] + bv[3]);
        uint2 u; u.x = pack2bf(v0, v1); u.y = pack2bf(v2, v3);
        *(uint2*)(slice + ((l15 * 256 + (ct * 16 + q * 4) * 2) ^ swz)) = u;
      }
    } else {
      #pragma unroll
      for (int ct = 0; ct < 8; ++ct)
        __builtin_nontemporal_store(acc[ct], (f32x4*)(outPtr + ct * 16));
    }
  }
}

// ---------------------------------------------------------------------------
// Angle branch (persistent): 256 blocks x 8 waves, 32 tiles of 16 rows/wave.
// ---------------------------------------------------------------------------
__global__ __launch_bounds__(512, 2) void angle_kernel(
    const float* __restrict__ m_ji, const float* __restrict__ a_sbf,
    const int* __restrict__ kj, const int* __restrict__ ji,
    const float* __restrict__ b1, const float* __restrict__ b2,
    const float* __restrict__ b3,
    const char* __restrict__ wfrag, const char* __restrict__ waT,
    float* __restrict__ out)
{
  extern __shared__ char lds[];
  char* Wb = lds;             // 128KB resident weights (frag-linear)
  char* xb = lds + 131072;    // 32KB x slices
  const int tid = threadIdx.x, lane = tid & 63, wave = tid >> 6;
  const int l15 = lane & 15, q = lane >> 4;
  const int swz = (l15 & 7) << 4;
  char* slice = xb + wave * 4096;

  #pragma unroll
  for (int i = 0; i < 16; ++i)
    gl_lds16(wfrag + (i * 512 + tid) * 16, Wb + (i * 512 + tid) * 16);

  bf16x8 wa[8][2];
  #pragma unroll
  for (int ct = 0; ct < 8; ++ct)
    #pragma unroll
    for (int ks = 0; ks < 2; ++ks)
      wa[ct][ks] = *(const bf16x8*)(waT + ((ct * 2 + ks) * 64 + lane) * 16);

  __syncthreads();  // weights staged; no barriers after this point

  const int wgid = blockIdx.x * 8 + wave;   // 0..2047
  const int t0 = wgid * 32;

  float as[16];
  f32x4 pk[8], pj[8];

  auto prefetch = [&](int t) {
    const int rb = t * 16;
    const int gr = rb + l15;
    const int ikj = kj[gr], iji = ji[gr];
    const float* bk = m_ji + (size_t)ikj * 128 + q * 4;
    const float* bj = m_ji + (size_t)iji * 128 + q * 4;
    #pragma unroll
    for (int ct = 0; ct < 8; ++ct) {
      pk[ct] = *(const f32x4*)(bk + ct * 16);
      pj[ct] = *(const f32x4*)(bj + ct * 16);
    }
    #pragma unroll
    for (int i = 0; i < 16; ++i)
      as[i] = (lane < 42)
          ? __builtin_nontemporal_load(a_sbf + (size_t)(rb + i) * 42 + lane)
          : 0.f;
  };

  prefetch(t0);
  for (int t = 0; t < 32; ++t) {
    const int rowbase = (t0 + t) * 16;

    // stage this tile's a_sbf rows [16][64] bf16 into slice (swizzled)
    #pragma unroll
    for (int i = 0; i < 16; ++i)
      *(unsigned short*)(slice + ((i * 128 + lane * 2) ^ ((i & 7) << 4))) =
          f2bf_u(as[i]);

    // projection fragments (same-wave DS ordering makes RAW safe)
    bf16x8 xf0 = *(const bf16x8*)(slice + ((l15 * 128 + q * 16) ^ swz));
    bf16x8 xf1 = *(const bf16x8*)(slice + ((l15 * 128 + 64 + q * 16) ^ swz));

    f32x4 gs[8];
    #pragma unroll
    for (int ct = 0; ct < 8; ++ct) gs[ct] = pk[ct] + pj[ct];

    f32x4 accp[8];
    #pragma unroll
    for (int ct = 0; ct < 8; ++ct) {
      f32x4 z = {0.f,0.f,0.f,0.f};
      z = __builtin_amdgcn_mfma_f32_16x16x32_bf16(wa[ct][0], xf0, z, 0, 0, 0);
      z = __builtin_amdgcn_mfma_f32_16x16x32_bf16(wa[ct][1], xf1, z, 0, 0, 0);
      accp[ct] = z;
    }

    // x0 = proj * gate  -> slice
    #pragma unroll
    for (int ct = 0; ct < 8; ++ct) {
      uint2 u;
      u.x = pack2bf(accp[ct][0] * gs[ct][0], accp[ct][1] * gs[ct][1]);
      u.y = pack2bf(accp[ct][2] * gs[ct][2], accp[ct][3] * gs[ct][3]);
      *(uint2*)(slice + ((l15 * 256 + (ct * 16 + q * 4) * 2) ^ swz)) = u;
    }

    // issue next tile's global loads; latency hides under the 4-layer MLP
    if (t < 31) prefetch(t0 + t + 1);

    mlp4_store(Wb, slice, b1, b2, b3,
               out + (size_t)(rowbase + l15) * 128 + q * 4, l15, q, lane, swz);
  }
}

// ---------------------------------------------------------------------------
// Edge branch (persistent): 256 blocks x 8 waves, 8 tiles of 16 rows/wave.
// proj via MFMA with K padded 6->32 (We^T frags in VGPRs).
// ---------------------------------------------------------------------------
__global__ __launch_bounds__(512, 2) void edge_kernel(
    const float* __restrict__ m_ji, const float* __restrict__ e_rbf,
    const float* __restrict__ b1, const float* __restrict__ b2,
    const float* __restrict__ b3,
    const char* __restrict__ wfrag, const char* __restrict__ weT,
    float* __restrict__ out)
{
  extern __shared__ char lds[];
  char* Wb = lds;
  char* xb = lds + 131072;
  const int tid = threadIdx.x, lane = tid & 63, wave = tid >> 6;
  const int l15 = lane & 15, q = lane >> 4;
  const int swz = (l15 & 7) << 4;
  char* slice = xb + wave * 4096;

  #pragma unroll
  for (int i = 0; i < 16; ++i)
    gl_lds16(wfrag + (i * 512 + tid) * 16, Wb + (i * 512 + tid) * 16);

  bf16x8 we[8];
  #pragma unroll
  for (int ct = 0; ct < 8; ++ct)
    we[ct] = *(const bf16x8*)(weT + (ct * 64 + lane) * 16);

  __syncthreads();

  const int wgid = blockIdx.x * 8 + wave;
  const int t0 = wgid * 8;

  float er[6];
  f32x4 mr[8];
  auto prefetch = [&](int t) {
    const int row = t * 16 + l15;
    #pragma unroll
    for (int j = 0; j < 6; ++j) er[j] = e_rbf[(size_t)row * 6 + j];
    const float* bm = m_ji + (size_t)row * 128 + q * 4;
    #pragma unroll
    for (int ct = 0; ct < 8; ++ct) mr[ct] = *(const f32x4*)(bm + ct * 16);
  };

  prefetch(t0);
  for (int t = 0; t < 8; ++t) {
    const int rowbase = (t0 + t) * 16;

    // e_rbf fragment: only q==0 lanes carry k<6, rest zero
    bf16x8 ef;
    #pragma unroll
    for (int j = 0; j < 8; ++j) {
      unsigned short h = (j < 6 && q == 0) ? f2bf_u(er[j]) : (unsigned short)0;
      ef[j] = (short)h;
    }

    f32x4 gs[8];
    #pragma unroll
    for (int ct = 0; ct < 8; ++ct) gs[ct] = mr[ct];

    // x0 = (e_rbf @ We) * m_ji -> slice
    #pragma unroll
    for (int ct = 0; ct < 8; ++ct) {
      f32x4 z = {0.f,0.f,0.f,0.f};
      z = __builtin_amdgcn_mfma_f32_16x16x32_bf16(we[ct], ef, z, 0, 0, 0);
      uint2 u;
      u.x = pack2bf(z[0] * gs[ct][0], z[1] * gs[ct][1]);
      u.y = pack2bf(z[2] * gs[ct][2], z[3] * gs[ct][3]);
      *(uint2*)(slice + ((l15 * 256 + (ct * 16 + q * 4) * 2) ^ swz)) = u;
    }

    if (t < 7) prefetch(t0 + t + 1);

    mlp4_store(Wb, slice, b1, b2, b3,
               out + (size_t)(rowbase + l15) * 128 + q * 4, l15, q, lane, swz);
  }
}

// ---------------------------------------------------------------------------
// Prep: bf16 weights into fragment-linear layouts in d_ws.
//  [0,128K):      edge W1..W4 frags  [mat][ct][ks][lane] 16B
//  [128K,256K):   angle W1..W4 frags
//  [256K,272K):   Wa^T proj frags [ct][ks0..1][lane]  (K pad 42->64)
//  [272K,276K):   We^T proj frags [ct][lane]          (K pad 6->32)
// frag(lane; n = ct*16+l15, k = ks*32+q*8+j) = W[k][n]
// ---------------------------------------------------------------------------
__global__ void prep_kernel(
    const float* __restrict__ W0, const float* __restrict__ W1,
    const float* __restrict__ W2, const float* __restrict__ W3,
    const float* __restrict__ W4, const float* __restrict__ W5,
    const float* __restrict__ W6, const float* __restrict__ W7,
    const float* __restrict__ Wa, const float* __restrict__ We,
    char* __restrict__ ws)
{
  const int gid = blockIdx.x * 256 + threadIdx.x;
  const int lane = gid & 63;
  const int l15 = lane & 15, q = lane >> 4;
  if (gid < 16384) {                       // 8 mats x 8ct x 4ks x 64 lanes
    const int mat = gid >> 11;
    const int ctks = (gid & 2047) >> 6;    // ct*4+ks
    const int n = (ctks >> 2) * 16 + l15;
    const int k0 = (ctks & 3) * 32 + q * 8;
    const float* W;
    switch (mat) {
      case 0: W = W0; break; case 1: W = W1; break;
      case 2: W = W2; break; case 3: W = W3; break;
      case 4: W = W4; break; case 5: W = W5; break;
      case 6: W = W6; break; default: W = W7; break;
    }
    us8 v;
    #pragma unroll
    for (int j = 0; j < 8; ++j) v[j] = f2bf_u(W[(size_t)(k0 + j) * 128 + n]);
    *(us8*)(ws + mat * 32768 + ctks * 1024 + lane * 16) = v;
  } else if (gid < 17408) {                // Wa proj: 8ct x 2ks x 64
    const int g = gid - 16384;
    const int ctks = g >> 6;               // ct*2+ks
    const int n = (ctks >> 1) * 16 + l15;
    const int k0 = (ctks & 1) * 32 + q * 8;
    us8 v;
    #pragma unroll
    for (int j = 0; j < 8; ++j) {
      const int k = k0 + j;
      v[j] = (k < 42) ? f2bf_u(Wa[(size_t)k * 128 + n]) : (unsigned short)0;
    }
    *(us8*)(ws + 262144 + ctks * 1024 + lane * 16) = v;
  } else if (gid < 17920) {                // We proj: 8ct x 64
    const int g = gid - 17408;
    const int ct = g >> 6;
    const int n = ct * 16 + l15;
    const int k0 = q * 8;
    us8 v;
    #pragma unroll
    for (int j = 0; j < 8; ++j) {
      const int k = k0 + j;
      v[j] = (k < 6) ? f2bf_u(We[(size_t)k * 128 + n]) : (unsigned short)0;
    }
    *(us8*)(ws + 278528 + ct * 1024 + lane * 16) = v;
  }
}

extern "C" void kernel_launch(void* const* d_in, const int* in_sizes, int n_in,
                              void* d_out, int out_size, void* d_ws, size_t ws_size,
                              hipStream_t stream) {
  (void)in_sizes; (void)n_in; (void)out_size; (void)ws_size;
  const float* m_ji  = (const float*)d_in[0];
  const float* e_rbf = (const float*)d_in[1];
  const float* a_sbf = (const float*)d_in[2];
  const int*   kj    = (const int*)d_in[4];
  const int*   ji    = (const int*)d_in[5];
  const float* We    = (const float*)d_in[6];
  const float* We1   = (const float*)d_in[7];
  const float* be1   = (const float*)d_in[8];
  const float* We2   = (const float*)d_in[9];
  const float* be2   = (const float*)d_in[10];
  const float* We3   = (const float*)d_in[11];
  const float* be3   = (const float*)d_in[12];
  const float* We4   = (const float*)d_in[13];
  const float* Wa    = (const float*)d_in[14];
  const float* Wa1   = (const float*)d_in[15];
  const float* ba1   = (const float*)d_in[16];
  const float* Wa2   = (const float*)d_in[17];
  const float* ba2   = (const float*)d_in[18];
  const float* Wa3   = (const float*)d_in[19];
  const float* ba3   = (const float*)d_in[20];
  const float* Wa4   = (const float*)d_in[21];
  char* ws = (char*)d_ws;
  float* out = (float*)d_out;

  // allow 160KB dynamic LDS (idempotent; not a stream op, graph-capture safe)
  hipFuncSetAttribute((const void*)edge_kernel,
                      hipFuncAttributeMaxDynamicSharedMemorySize, 163840);
  hipFuncSetAttribute((const void*)angle_kernel,
                      hipFuncAttributeMaxDynamicSharedMemorySize, 163840);

  prep_kernel<<<70, 256, 0, stream>>>(
      We1, We2, We3, We4, Wa1, Wa2, Wa3, Wa4, Wa, We, ws);
  edge_kernel<<<256, 512, 163840, stream>>>(
      m_ji, e_rbf, be1, be2, be3, ws, ws + 278528, out);
  angle_kernel<<<256, 512, 163840, stream>>>(
      m_ji, a_sbf, kj, ji, ba1, ba2, ba3, ws + 131072, ws + 262144,
      out + (size_t)262144 * 128);
}

// Round 5
// 632.648 us; speedup vs baseline: 1.8992x; 1.8992x over previous
//
#include <hip/hip_runtime.h>
#include <stdint.h>

typedef __attribute__((ext_vector_type(8))) short bf16x8;
typedef __attribute__((ext_vector_type(4))) float f32x4;
typedef __attribute__((ext_vector_type(8))) unsigned short us8;

static __device__ __forceinline__ unsigned short f2bf_u(float f) {
  __bf16 h = (__bf16)f;
  return __builtin_bit_cast(unsigned short, h);
}
static __device__ __forceinline__ uint32_t pack2bf(float a, float b) {
  return (uint32_t)f2bf_u(a) | ((uint32_t)f2bf_u(b) << 16);
}
static __device__ __forceinline__ float silu_f(float v) {
  float e = __builtin_amdgcn_exp2f(v * -1.44269504088896341f);
  return v * __builtin_amdgcn_rcpf(1.0f + e);
}

// ---------------------------------------------------------------------------
// One MLP layer, x-shared: wave w computes cols [w*16,w*16+16) for all 128
// rows of the tile. src/dst are 32KB bf16 [128][256B] XOR-swizzled LDS.
// Weights for this layer/wave are 4 VGPR-resident fragments (wf[ks]).
// ---------------------------------------------------------------------------
template<bool LAST>
static __device__ __forceinline__ void xlayer(
    const char* __restrict__ src, char* __restrict__ dst,
    const bf16x8* wf, const float* __restrict__ bias,
    float* __restrict__ gout, int l15, int q, int w, int rs)
{
  f32x4 bv;
  if (!LAST) bv = *(const f32x4*)(bias + w * 16 + q * 4);
  #pragma unroll
  for (int rg = 0; rg < 8; ++rg) {
    const int row = rg * 16 + l15;
    f32x4 acc = {0.f, 0.f, 0.f, 0.f};
    #pragma unroll
    for (int ks = 0; ks < 4; ++ks) {
      bf16x8 xf = *(const bf16x8*)(src + ((row * 256 + ks * 64 + q * 16) ^ rs));
      acc = __builtin_amdgcn_mfma_f32_16x16x32_bf16(wf[ks], xf, acc, 0, 0, 0);
    }
    if (!LAST) {
      float v0 = silu_f(acc[0] + bv[0]);
      float v1 = silu_f(acc[1] + bv[1]);
      float v2 = silu_f(acc[2] + bv[2]);
      float v3 = silu_f(acc[3] + bv[3]);
      uint2 u; u.x = pack2bf(v0, v1); u.y = pack2bf(v2, v3);
      *(uint2*)(dst + ((row * 256 + w * 32 + q * 8) ^ rs)) = u;
    } else {
      __builtin_nontemporal_store(acc,
          (f32x4*)(gout + (size_t)row * 128 + w * 16 + q * 4));
    }
  }
}

// ---------------------------------------------------------------------------
// Angle branch: tile = 128 rows/block, 8 waves, x-shared, weights in VGPR.
// LDS: xbA 32K | xbB 32K | aux 16K (a_sbf frags) = 80K -> 2 blocks/CU.
// ---------------------------------------------------------------------------
__global__ __launch_bounds__(512, 4) void angle_kernel(
    const float* __restrict__ m_ji, const float* __restrict__ a_sbf,
    const int* __restrict__ kj, const int* __restrict__ ji,
    const float* __restrict__ b1, const float* __restrict__ b2,
    const float* __restrict__ b3,
    const char* __restrict__ wt4, const char* __restrict__ waT,
    float* __restrict__ out)
{
  extern __shared__ char lds[];
  char* xbA = lds;
  char* xbB = lds + 32768;
  char* aux = lds + 65536;
  const int tid = threadIdx.x, lane = tid & 63, w = tid >> 6;
  const int l15 = lane & 15, q = lane >> 4;
  const int rs = (l15 & 7) << 4;
  const size_t tb = (size_t)blockIdx.x * 128;

  // proj weights (8 VGPRs)
  bf16x8 wa0 = *(const bf16x8*)(waT + (w * 2 + 0) * 1024 + lane * 16);
  bf16x8 wa1 = *(const bf16x8*)(waT + (w * 2 + 1) * 1024 + lane * 16);

  // gather indices for all 8 row-groups (resolved during staging)
  int ikj[8], iji[8];
  #pragma unroll
  for (int i2 = 0; i2 < 8; ++i2) {
    ikj[i2] = kj[tb + i2 * 16 + l15];
    iji[i2] = ji[tb + i2 * 16 + l15];
  }

  // stage a_sbf tile -> aux bf16 frags [128][64] swizzled (pad 42->64)
  {
    const float* src = a_sbf + tb * 42;
    #pragma unroll
    for (int j2 = 0; j2 < 8; ++j2) {
      const int i = tid + j2 * 512;
      const int row = i >> 5, p = i & 31;
      const float* rp = src + row * 42 + p * 2;
      float v0 = (p * 2 < 42) ? __builtin_nontemporal_load(rp) : 0.f;
      float v1 = (p * 2 + 1 < 42) ? __builtin_nontemporal_load(rp + 1) : 0.f;
      *(uint32_t*)(aux + ((row * 128 + p * 4) ^ ((row & 7) << 4))) = pack2bf(v0, v1);
    }
  }
  __syncthreads();

  // proj + gather-gate -> x0 -> xbA  (gathers issued 2 row-groups ahead)
  {
    f32x4 pk[8], pj[8];
    auto gissue = [&](int g) {
      pk[g] = *(const f32x4*)(m_ji + (size_t)ikj[g] * 128 + w * 16 + q * 4);
      pj[g] = *(const f32x4*)(m_ji + (size_t)iji[g] * 128 + w * 16 + q * 4);
    };
    gissue(0); gissue(1);
    #pragma unroll
    for (int rg = 0; rg < 8; ++rg) {
      if (rg < 6) gissue(rg + 2);
      const int row = rg * 16 + l15;
      bf16x8 x0f = *(const bf16x8*)(aux + ((row * 128 + q * 16) ^ rs));
      bf16x8 x1f = *(const bf16x8*)(aux + ((row * 128 + 64 + q * 16) ^ rs));
      f32x4 acc = {0.f, 0.f, 0.f, 0.f};
      acc = __builtin_amdgcn_mfma_f32_16x16x32_bf16(wa0, x0f, acc, 0, 0, 0);
      acc = __builtin_amdgcn_mfma_f32_16x16x32_bf16(wa1, x1f, acc, 0, 0, 0);
      f32x4 g = pk[rg] + pj[rg];
      uint2 u;
      u.x = pack2bf(acc[0] * g[0], acc[1] * g[1]);
      u.y = pack2bf(acc[2] * g[2], acc[3] * g[3]);
      *(uint2*)(xbA + ((row * 256 + w * 32 + q * 8) ^ rs)) = u;
    }
  }
  __syncthreads();

  // MLP weights loaded after proj (keeps proj-phase VGPR pressure low)
  bf16x8 wfl[4][4];
  #pragma unroll
  for (int L = 0; L < 4; ++L)
    #pragma unroll
    for (int ks = 0; ks < 4; ++ks)
      wfl[L][ks] = *(const bf16x8*)(wt4 + L * 32768 + (w * 4 + ks) * 1024 + lane * 16);

  xlayer<false>(xbA, xbB, wfl[0], b1, nullptr, l15, q, w, rs);
  __syncthreads();
  xlayer<false>(xbB, xbA, wfl[1], b2, nullptr, l15, q, w, rs);
  __syncthreads();
  xlayer<false>(xbA, xbB, wfl[2], b3, nullptr, l15, q, w, rs);
  __syncthreads();
  xlayer<true>(xbB, nullptr, wfl[3], nullptr, out + tb * 128, l15, q, w, rs);
}

// ---------------------------------------------------------------------------
// Edge branch: same structure; proj is (e_rbf @ We) * m_ji, K padded 6->32.
// LDS: xbA 32K | xbB 32K | auxF 3K (e_rbf f32).
// ---------------------------------------------------------------------------
__global__ __launch_bounds__(512, 4) void edge_kernel(
    const float* __restrict__ m_ji, const float* __restrict__ e_rbf,
    const float* __restrict__ b1, const float* __restrict__ b2,
    const float* __restrict__ b3,
    const char* __restrict__ wt4, const char* __restrict__ weT,
    float* __restrict__ out)
{
  extern __shared__ char lds[];
  char* xbA = lds;
  char* xbB = lds + 32768;
  float* auxF = (float*)(lds + 65536);
  const int tid = threadIdx.x, lane = tid & 63, w = tid >> 6;
  const int l15 = lane & 15, q = lane >> 4;
  const int rs = (l15 & 7) << 4;
  const size_t tb = (size_t)blockIdx.x * 128;

  bf16x8 we = *(const bf16x8*)(weT + w * 1024 + lane * 16);

  // stage e_rbf tile (768 contiguous f32)
  {
    const float* src = e_rbf + tb * 6;
    auxF[tid] = __builtin_nontemporal_load(src + tid);
    const int i2 = tid + 512;
    if (i2 < 768) auxF[i2] = __builtin_nontemporal_load(src + i2);
  }
  __syncthreads();

  // proj + gate -> x0 -> xbA  (m_ji rows streamed, issued 2 rgs ahead)
  {
    f32x4 mr[8];
    auto missue = [&](int g) {
      mr[g] = *(const f32x4*)(m_ji + (tb + g * 16 + l15) * 128 + w * 16 + q * 4);
    };
    missue(0); missue(1);
    #pragma unroll
    for (int rg = 0; rg < 8; ++rg) {
      if (rg < 6) missue(rg + 2);
      const int row = rg * 16 + l15;
      bf16x8 ef;
      #pragma unroll
      for (int j = 0; j < 8; ++j) {
        float v = (j < 6) ? auxF[row * 6 + j] : 0.f;
        unsigned short h = (q == 0 && j < 6) ? f2bf_u(v) : (unsigned short)0;
        ef[j] = (short)h;
      }
      f32x4 acc = {0.f, 0.f, 0.f, 0.f};
      acc = __builtin_amdgcn_mfma_f32_16x16x32_bf16(we, ef, acc, 0, 0, 0);
      f32x4 g = mr[rg];
      uint2 u;
      u.x = pack2bf(acc[0] * g[0], acc[1] * g[1]);
      u.y = pack2bf(acc[2] * g[2], acc[3] * g[3]);
      *(uint2*)(xbA + ((row * 256 + w * 32 + q * 8) ^ rs)) = u;
    }
  }
  __syncthreads();

  bf16x8 wfl[4][4];
  #pragma unroll
  for (int L = 0; L < 4; ++L)
    #pragma unroll
    for (int ks = 0; ks < 4; ++ks)
      wfl[L][ks] = *(const bf16x8*)(wt4 + L * 32768 + (w * 4 + ks) * 1024 + lane * 16);

  xlayer<false>(xbA, xbB, wfl[0], b1, nullptr, l15, q, w, rs);
  __syncthreads();
  xlayer<false>(xbB, xbA, wfl[1], b2, nullptr, l15, q, w, rs);
  __syncthreads();
  xlayer<false>(xbA, xbB, wfl[2], b3, nullptr, l15, q, w, rs);
  __syncthreads();
  xlayer<true>(xbB, nullptr, wfl[3], nullptr, out + tb * 128, l15, q, w, rs);
}

// ---------------------------------------------------------------------------
// Prep: bf16 weights into fragment-linear layouts in d_ws.
//  [0,128K):    edge W1..W4 frags [mat][ct*4+ks][lane]16B
//  [128K,256K): angle W1..W4 frags
//  [256K,272K): Wa proj frags [ct*2+ks][lane]  (K pad 42->64)
//  [272K,276K): We proj frags [ct][lane]       (K pad 6->32)
// frag(lane; n = ct*16+l15, k = ks*32+q*8+j) = W[k][n]
// ---------------------------------------------------------------------------
__global__ void prep_kernel(
    const float* __restrict__ W0, const float* __restrict__ W1,
    const float* __restrict__ W2, const float* __restrict__ W3,
    const float* __restrict__ W4, const float* __restrict__ W5,
    const float* __restrict__ W6, const float* __restrict__ W7,
    const float* __restrict__ Wa, const float* __restrict__ We,
    char* __restrict__ ws)
{
  const int gid = blockIdx.x * 256 + threadIdx.x;
  const int lane = gid & 63;
  const int l15 = lane & 15, q = lane >> 4;
  if (gid < 16384) {
    const int mat = gid >> 11;
    const int ctks = (gid & 2047) >> 6;
    const int n = (ctks >> 2) * 16 + l15;
    const int k0 = (ctks & 3) * 32 + q * 8;
    const float* W;
    switch (mat) {
      case 0: W = W0; break; case 1: W = W1; break;
      case 2: W = W2; break; case 3: W = W3; break;
      case 4: W = W4; break; case 5: W = W5; break;
      case 6: W = W6; break; default: W = W7; break;
    }
    us8 v;
    #pragma unroll
    for (int j = 0; j < 8; ++j) v[j] = f2bf_u(W[(size_t)(k0 + j) * 128 + n]);
    *(us8*)(ws + mat * 32768 + ctks * 1024 + lane * 16) = v;
  } else if (gid < 17408) {
    const int g = gid - 16384;
    const int ctks = g >> 6;
    const int n = (ctks >> 1) * 16 + l15;
    const int k0 = (ctks & 1) * 32 + q * 8;
    us8 v;
    #pragma unroll
    for (int j = 0; j < 8; ++j) {
      const int k = k0 + j;
      v[j] = (k < 42) ? f2bf_u(Wa[(size_t)k * 128 + n]) : (unsigned short)0;
    }
    *(us8*)(ws + 262144 + ctks * 1024 + lane * 16) = v;
  } else if (gid < 17920) {
    const int g = gid - 17408;
    const int ct = g >> 6;
    const int n = ct * 16 + l15;
    const int k0 = q * 8;
    us8 v;
    #pragma unroll
    for (int j = 0; j < 8; ++j) {
      const int k = k0 + j;
      v[j] = (k < 6) ? f2bf_u(We[(size_t)k * 128 + n]) : (unsigned short)0;
    }
    *(us8*)(ws + 278528 + ct * 1024 + lane * 16) = v;
  }
}

extern "C" void kernel_launch(void* const* d_in, const int* in_sizes, int n_in,
                              void* d_out, int out_size, void* d_ws, size_t ws_size,
                              hipStream_t stream) {
  (void)in_sizes; (void)n_in; (void)out_size; (void)ws_size;
  const float* m_ji  = (const float*)d_in[0];
  const float* e_rbf = (const float*)d_in[1];
  const float* a_sbf = (const float*)d_in[2];
  const int*   kj    = (const int*)d_in[4];
  const int*   ji    = (const int*)d_in[5];
  const float* We    = (const float*)d_in[6];
  const float* We1   = (const float*)d_in[7];
  const float* be1   = (const float*)d_in[8];
  const float* We2   = (const float*)d_in[9];
  const float* be2   = (const float*)d_in[10];
  const float* We3   = (const float*)d_in[11];
  const float* be3   = (const float*)d_in[12];
  const float* We4   = (const float*)d_in[13];
  const float* Wa    = (const float*)d_in[14];
  const float* Wa1   = (const float*)d_in[15];
  const float* ba1   = (const float*)d_in[16];
  const float* Wa2   = (const float*)d_in[17];
  const float* ba2   = (const float*)d_in[18];
  const float* Wa3   = (const float*)d_in[19];
  const float* ba3   = (const float*)d_in[20];
  const float* Wa4   = (const float*)d_in[21];
  char* ws = (char*)d_ws;
  float* out = (float*)d_out;

  hipFuncSetAttribute((const void*)edge_kernel,
                      hipFuncAttributeMaxDynamicSharedMemorySize, 68608);
  hipFuncSetAttribute((const void*)angle_kernel,
                      hipFuncAttributeMaxDynamicSharedMemorySize, 81920);

  prep_kernel<<<70, 256, 0, stream>>>(
      We1, We2, We3, We4, Wa1, Wa2, Wa3, Wa4, Wa, We, ws);
  edge_kernel<<<262144 / 128, 512, 68608, stream>>>(
      m_ji, e_rbf, be1, be2, be3, ws, ws + 278528, out);
  angle_kernel<<<1048576 / 128, 512, 81920, stream>>>(
      m_ji, a_sbf, kj, ji, ba1, ba2, ba3, ws + 131072, ws + 262144,
      out + (size_t)262144 * 128);
}

// Round 6
// 612.993 us; speedup vs baseline: 1.9601x; 1.0321x over previous
//
#include <hip/hip_runtime.h>
#include <stdint.h>

typedef __attribute__((ext_vector_type(8))) short bf16x8;
typedef __attribute__((ext_vector_type(4))) float f32x4;
typedef __attribute__((ext_vector_type(8))) unsigned short us8;

static __device__ __forceinline__ unsigned short f2bf_u(float f) {
  __bf16 h = (__bf16)f;
  return __builtin_bit_cast(unsigned short, h);
}
static __device__ __forceinline__ uint32_t pack2bf(float a, float b) {
  return (uint32_t)f2bf_u(a) | ((uint32_t)f2bf_u(b) << 16);
}
static __device__ __forceinline__ float silu_f(float v) {
  float e = __builtin_amdgcn_exp2f(v * -1.44269504088896341f);
  return v * __builtin_amdgcn_rcpf(1.0f + e);
}

// ---------------------------------------------------------------------------
// One MLP layer, x-shared: wave w computes cols [w*16,w*16+16) for all 128
// rows of the tile. src/dst are 32KB bf16 [128][256B] XOR-swizzled LDS.
// Weights for this layer/wave are 4 VGPR-resident fragments (wf[ks]).
// ---------------------------------------------------------------------------
template<bool LAST>
static __device__ __forceinline__ void xlayer(
    const char* __restrict__ src, char* __restrict__ dst,
    const bf16x8* wf, const float* __restrict__ bias,
    float* __restrict__ gout, int l15, int q, int w, int rs)
{
  f32x4 bv;
  if (!LAST) bv = *(const f32x4*)(bias + w * 16 + q * 4);
  #pragma unroll
  for (int rg = 0; rg < 8; ++rg) {
    const int row = rg * 16 + l15;
    f32x4 acc = {0.f, 0.f, 0.f, 0.f};
    #pragma unroll
    for (int ks = 0; ks < 4; ++ks) {
      bf16x8 xf = *(const bf16x8*)(src + ((row * 256 + ks * 64 + q * 16) ^ rs));
      acc = __builtin_amdgcn_mfma_f32_16x16x32_bf16(wf[ks], xf, acc, 0, 0, 0);
    }
    if (!LAST) {
      float v0 = silu_f(acc[0] + bv[0]);
      float v1 = silu_f(acc[1] + bv[1]);
      float v2 = silu_f(acc[2] + bv[2]);
      float v3 = silu_f(acc[3] + bv[3]);
      uint2 u; u.x = pack2bf(v0, v1); u.y = pack2bf(v2, v3);
      *(uint2*)(dst + ((row * 256 + w * 32 + q * 8) ^ rs)) = u;
    } else {
      __builtin_nontemporal_store(acc,
          (f32x4*)(gout + (size_t)row * 128 + w * 16 + q * 4));
    }
  }
}

// ---------------------------------------------------------------------------
// Angle branch: tile = 128 rows/block, 8 waves, x-shared, weights in VGPR.
// LDS: xbA 32K | xbB 32K | aux 16K = 80K -> 2 blocks/CU.
// All 16 m_ji gathers issued upfront (64 VGPRs in flight), pinned by
// sched_barrier so their HBM latency hides under a_sbf staging + barrier.
// wfl loads pinned AFTER proj so they can't hoist and blow the register
// budget (R5: compiler spilled pk/pj -> 276MB scratch writes).
// ---------------------------------------------------------------------------
__global__ __launch_bounds__(512, 4) void angle_kernel(
    const float* __restrict__ m_ji, const float* __restrict__ a_sbf,
    const int* __restrict__ kj, const int* __restrict__ ji,
    const float* __restrict__ b1, const float* __restrict__ b2,
    const float* __restrict__ b3,
    const char* __restrict__ wt4, const char* __restrict__ waT,
    float* __restrict__ out)
{
  extern __shared__ char lds[];
  char* xbA = lds;
  char* xbB = lds + 32768;
  char* aux = lds + 65536;
  const int tid = threadIdx.x, lane = tid & 63, w = tid >> 6;
  const int l15 = lane & 15, q = lane >> 4;
  const int rs = (l15 & 7) << 4;
  const size_t tb = (size_t)blockIdx.x * 128;

  // proj weights (8 VGPRs)
  bf16x8 wa0 = *(const bf16x8*)(waT + (w * 2 + 0) * 1024 + lane * 16);
  bf16x8 wa1 = *(const bf16x8*)(waT + (w * 2 + 1) * 1024 + lane * 16);

  // gather indices
  int ikj[8], iji[8];
  #pragma unroll
  for (int g = 0; g < 8; ++g) {
    ikj[g] = kj[tb + g * 16 + l15];
    iji[g] = ji[tb + g * 16 + l15];
  }

  // issue ALL gathers now; keep in flight across the staging phase
  f32x4 pk[8], pj[8];
  #pragma unroll
  for (int g = 0; g < 8; ++g) {
    pk[g] = *(const f32x4*)(m_ji + (size_t)ikj[g] * 128 + w * 16 + q * 4);
    pj[g] = *(const f32x4*)(m_ji + (size_t)iji[g] * 128 + w * 16 + q * 4);
  }
  __builtin_amdgcn_sched_barrier(0);

  // stage a_sbf tile -> aux bf16 frags [128][64] swizzled (pad 42->64)
  {
    const float* src = a_sbf + tb * 42;
    #pragma unroll
    for (int j2 = 0; j2 < 8; ++j2) {
      const int i = tid + j2 * 512;
      const int row = i >> 5, p = i & 31;
      const float* rp = src + row * 42 + p * 2;
      float v0 = (p * 2 < 42) ? __builtin_nontemporal_load(rp) : 0.f;
      float v1 = (p * 2 + 1 < 42) ? __builtin_nontemporal_load(rp + 1) : 0.f;
      *(uint32_t*)(aux + ((row * 128 + p * 4) ^ ((row & 7) << 4))) = pack2bf(v0, v1);
    }
  }
  __syncthreads();

  // proj + gather-gate -> x0 -> xbA
  #pragma unroll
  for (int rg = 0; rg < 8; ++rg) {
    const int row = rg * 16 + l15;
    bf16x8 x0f = *(const bf16x8*)(aux + ((row * 128 + q * 16) ^ rs));
    bf16x8 x1f = *(const bf16x8*)(aux + ((row * 128 + 64 + q * 16) ^ rs));
    f32x4 acc = {0.f, 0.f, 0.f, 0.f};
    acc = __builtin_amdgcn_mfma_f32_16x16x32_bf16(wa0, x0f, acc, 0, 0, 0);
    acc = __builtin_amdgcn_mfma_f32_16x16x32_bf16(wa1, x1f, acc, 0, 0, 0);
    f32x4 g = pk[rg] + pj[rg];
    uint2 u;
    u.x = pack2bf(acc[0] * g[0], acc[1] * g[1]);
    u.y = pack2bf(acc[2] * g[2], acc[3] * g[3]);
    *(uint2*)(xbA + ((row * 256 + w * 32 + q * 8) ^ rs)) = u;
  }
  __builtin_amdgcn_sched_barrier(0);

  // MLP weights loaded only now (pk/pj dead -> fits 128-reg budget);
  // latency hides under the barrier + layer-0 LDS reads.
  bf16x8 wfl[4][4];
  #pragma unroll
  for (int L = 0; L < 4; ++L)
    #pragma unroll
    for (int ks = 0; ks < 4; ++ks)
      wfl[L][ks] = *(const bf16x8*)(wt4 + L * 32768 + (w * 4 + ks) * 1024 + lane * 16);

  __syncthreads();

  xlayer<false>(xbA, xbB, wfl[0], b1, nullptr, l15, q, w, rs);
  __syncthreads();
  xlayer<false>(xbB, xbA, wfl[1], b2, nullptr, l15, q, w, rs);
  __syncthreads();
  xlayer<false>(xbA, xbB, wfl[2], b3, nullptr, l15, q, w, rs);
  __syncthreads();
  xlayer<true>(xbB, nullptr, wfl[3], nullptr, out + tb * 128, l15, q, w, rs);
}

// ---------------------------------------------------------------------------
// Edge branch: same structure; proj is (e_rbf @ We) * m_ji, K padded 6->32.
// ---------------------------------------------------------------------------
__global__ __launch_bounds__(512, 4) void edge_kernel(
    const float* __restrict__ m_ji, const float* __restrict__ e_rbf,
    const float* __restrict__ b1, const float* __restrict__ b2,
    const float* __restrict__ b3,
    const char* __restrict__ wt4, const char* __restrict__ weT,
    float* __restrict__ out)
{
  extern __shared__ char lds[];
  char* xbA = lds;
  char* xbB = lds + 32768;
  float* auxF = (float*)(lds + 65536);
  const int tid = threadIdx.x, lane = tid & 63, w = tid >> 6;
  const int l15 = lane & 15, q = lane >> 4;
  const int rs = (l15 & 7) << 4;
  const size_t tb = (size_t)blockIdx.x * 128;

  bf16x8 we = *(const bf16x8*)(weT + w * 1024 + lane * 16);

  // issue all m_ji row loads upfront (32 VGPRs), pinned
  f32x4 mr[8];
  #pragma unroll
  for (int g = 0; g < 8; ++g)
    mr[g] = *(const f32x4*)(m_ji + (tb + g * 16 + l15) * 128 + w * 16 + q * 4);
  __builtin_amdgcn_sched_barrier(0);

  // stage e_rbf tile (768 contiguous f32)
  {
    const float* src = e_rbf + tb * 6;
    auxF[tid] = __builtin_nontemporal_load(src + tid);
    const int i2 = tid + 512;
    if (i2 < 768) auxF[i2] = __builtin_nontemporal_load(src + i2);
  }
  __syncthreads();

  // proj + gate -> x0 -> xbA
  #pragma unroll
  for (int rg = 0; rg < 8; ++rg) {
    const int row = rg * 16 + l15;
    bf16x8 ef;
    #pragma unroll
    for (int j = 0; j < 8; ++j) {
      float v = (j < 6) ? auxF[row * 6 + j] : 0.f;
      unsigned short h = (q == 0 && j < 6) ? f2bf_u(v) : (unsigned short)0;
      ef[j] = (short)h;
    }
    f32x4 acc = {0.f, 0.f, 0.f, 0.f};
    acc = __builtin_amdgcn_mfma_f32_16x16x32_bf16(we, ef, acc, 0, 0, 0);
    f32x4 g = mr[rg];
    uint2 u;
    u.x = pack2bf(acc[0] * g[0], acc[1] * g[1]);
    u.y = pack2bf(acc[2] * g[2], acc[3] * g[3]);
    *(uint2*)(xbA + ((row * 256 + w * 32 + q * 8) ^ rs)) = u;
  }
  __builtin_amdgcn_sched_barrier(0);

  bf16x8 wfl[4][4];
  #pragma unroll
  for (int L = 0; L < 4; ++L)
    #pragma unroll
    for (int ks = 0; ks < 4; ++ks)
      wfl[L][ks] = *(const bf16x8*)(wt4 + L * 32768 + (w * 4 + ks) * 1024 + lane * 16);

  __syncthreads();

  xlayer<false>(xbA, xbB, wfl[0], b1, nullptr, l15, q, w, rs);
  __syncthreads();
  xlayer<false>(xbB, xbA, wfl[1], b2, nullptr, l15, q, w, rs);
  __syncthreads();
  xlayer<false>(xbA, xbB, wfl[2], b3, nullptr, l15, q, w, rs);
  __syncthreads();
  xlayer<true>(xbB, nullptr, wfl[3], nullptr, out + tb * 128, l15, q, w, rs);
}

// ---------------------------------------------------------------------------
// Prep: bf16 weights into fragment-linear layouts in d_ws.
//  [0,128K):    edge W1..W4 frags [mat][ct*4+ks][lane]16B
//  [128K,256K): angle W1..W4 frags
//  [256K,272K): Wa proj frags [ct*2+ks][lane]  (K pad 42->64)
//  [272K,276K): We proj frags [ct][lane]       (K pad 6->32)
// frag(lane; n = ct*16+l15, k = ks*32+q*8+j) = W[k][n]
// ---------------------------------------------------------------------------
__global__ void prep_kernel(
    const float* __restrict__ W0, const float* __restrict__ W1,
    const float* __restrict__ W2, const float* __restrict__ W3,
    const float* __restrict__ W4, const float* __restrict__ W5,
    const float* __restrict__ W6, const float* __restrict__ W7,
    const float* __restrict__ Wa, const float* __restrict__ We,
    char* __restrict__ ws)
{
  const int gid = blockIdx.x * 256 + threadIdx.x;
  const int lane = gid & 63;
  const int l15 = lane & 15, q = lane >> 4;
  if (gid < 16384) {
    const int mat = gid >> 11;
    const int ctks = (gid & 2047) >> 6;
    const int n = (ctks >> 2) * 16 + l15;
    const int k0 = (ctks & 3) * 32 + q * 8;
    const float* W;
    switch (mat) {
      case 0: W = W0; break; case 1: W = W1; break;
      case 2: W = W2; break; case 3: W = W3; break;
      case 4: W = W4; break; case 5: W = W5; break;
      case 6: W = W6; break; default: W = W7; break;
    }
    us8 v;
    #pragma unroll
    for (int j = 0; j < 8; ++j) v[j] = f2bf_u(W[(size_t)(k0 + j) * 128 + n]);
    *(us8*)(ws + mat * 32768 + ctks * 1024 + lane * 16) = v;
  } else if (gid < 17408) {
    const int g = gid - 16384;
    const int ctks = g >> 6;
    const int n = (ctks >> 1) * 16 + l15;
    const int k0 = (ctks & 1) * 32 + q * 8;
    us8 v;
    #pragma unroll
    for (int j = 0; j < 8; ++j) {
      const int k = k0 + j;
      v[j] = (k < 42) ? f2bf_u(Wa[(size_t)k * 128 + n]) : (unsigned short)0;
    }
    *(us8*)(ws + 262144 + ctks * 1024 + lane * 16) = v;
  } else if (gid < 17920) {
    const int g = gid - 17408;
    const int ct = g >> 6;
    const int n = ct * 16 + l15;
    const int k0 = q * 8;
    us8 v;
    #pragma unroll
    for (int j = 0; j < 8; ++j) {
      const int k = k0 + j;
      v[j] = (k < 6) ? f2bf_u(We[(size_t)k * 128 + n]) : (unsigned short)0;
    }
    *(us8*)(ws + 278528 + ct * 1024 + lane * 16) = v;
  }
}

extern "C" void kernel_launch(void* const* d_in, const int* in_sizes, int n_in,
                              void* d_out, int out_size, void* d_ws, size_t ws_size,
                              hipStream_t stream) {
  (void)in_sizes; (void)n_in; (void)out_size; (void)ws_size;
  const float* m_ji  = (const float*)d_in[0];
  const float* e_rbf = (const float*)d_in[1];
  const float* a_sbf = (const float*)d_in[2];
  const int*   kj    = (const int*)d_in[4];
  const int*   ji    = (const int*)d_in[5];
  const float* We    = (const float*)d_in[6];
  const float* We1   = (const float*)d_in[7];
  const float* be1   = (const float*)d_in[8];
  const float* We2   = (const float*)d_in[9];
  const float* be2   = (const float*)d_in[10];
  const float* We3   = (const float*)d_in[11];
  const float* be3   = (const float*)d_in[12];
  const float* We4   = (const float*)d_in[13];
  const float* Wa    = (const float*)d_in[14];
  const float* Wa1   = (const float*)d_in[15];
  const float* ba1   = (const float*)d_in[16];
  const float* Wa2   = (const float*)d_in[17];
  const float* ba2   = (const float*)d_in[18];
  const float* Wa3   = (const float*)d_in[19];
  const float* ba3   = (const float*)d_in[20];
  const float* Wa4   = (const float*)d_in[21];
  char* ws = (char*)d_ws;
  float* out = (float*)d_out;

  hipFuncSetAttribute((const void*)edge_kernel,
                      hipFuncAttributeMaxDynamicSharedMemorySize, 68608);
  hipFuncSetAttribute((const void*)angle_kernel,
                      hipFuncAttributeMaxDynamicSharedMemorySize, 81920);

  prep_kernel<<<70, 256, 0, stream>>>(
      We1, We2, We3, We4, Wa1, Wa2, Wa3, Wa4, Wa, We, ws);
  edge_kernel<<<262144 / 128, 512, 68608, stream>>>(
      m_ji, e_rbf, be1, be2, be3, ws, ws + 278528, out);
  angle_kernel<<<1048576 / 128, 512, 81920, stream>>>(
      m_ji, a_sbf, kj, ji, ba1, ba2, ba3, ws + 131072, ws + 262144,
      out + (size_t)262144 * 128);
}